// Round 1
// baseline (481.746 us; speedup 1.0000x reference)
//
#include <hip/hip_runtime.h>
#include <stdint.h>

#define B_   4
#define S_   2048
#define DI   1024
#define DOUT 1024
#define NHD  16
#define HD   64

typedef __attribute__((ext_vector_type(8))) short short8;
typedef __attribute__((ext_vector_type(4))) float f32x4;

__device__ __forceinline__ unsigned short f32_bf16(float f) {
  union { float f; unsigned u; } v; v.f = f;
  unsigned r = v.u + 0x7FFFu + ((v.u >> 16) & 1u);   // RNE
  return (unsigned short)(r >> 16);
}

// ---------- elementwise fp32 -> bf16 ----------
__global__ __launch_bounds__(256) void cvt_kernel(const float* __restrict__ src,
                                                  unsigned short* __restrict__ dst, int n4) {
  int i = blockIdx.x * blockDim.x + threadIdx.x;
  if (i < n4) {
    float4 v = ((const float4*)src)[i];
    ushort4 o;
    o.x = f32_bf16(v.x); o.y = f32_bf16(v.y); o.z = f32_bf16(v.z); o.w = f32_bf16(v.w);
    ((ushort4*)dst)[i] = o;
  }
}

// ---------- weight transpose+convert: W[k][n] f32 -> Wt[n][k] bf16 ----------
__global__ __launch_bounds__(256) void wtrans_kernel(const float* __restrict__ W,
                                                     unsigned short* __restrict__ Wt) {
  __shared__ __attribute__((aligned(16))) float tile[64][65];
  const int k0 = blockIdx.y * 64;
  const int n0 = blockIdx.x * 64;
  const int tid = threadIdx.x;
#pragma unroll
  for (int i = 0; i < 4; i++) {
    int c = tid + i * 256;
    int r = c >> 4;            // k-local
    int cc = (c & 15) * 4;     // n-local
    float4 v = *(const float4*)(W + (size_t)(k0 + r) * DOUT + n0 + cc);
    tile[r][cc] = v.x; tile[r][cc + 1] = v.y; tile[r][cc + 2] = v.z; tile[r][cc + 3] = v.w;
  }
  __syncthreads();
#pragma unroll
  for (int i = 0; i < 4; i++) {
    int c = tid + i * 256;
    int r = c >> 4;            // n-local
    int cc = (c & 15) * 4;     // k-local
    ushort4 o;
    o.x = f32_bf16(tile[cc + 0][r]);
    o.y = f32_bf16(tile[cc + 1][r]);
    o.z = f32_bf16(tile[cc + 2][r]);
    o.w = f32_bf16(tile[cc + 3][r]);
    *(ushort4*)(Wt + (size_t)(n0 + r) * DI + k0 + cc) = o;
  }
}

// ---------- V transpose: Vb[bh][s][hd] -> Vt[bh][hd][s] (bf16) ----------
__global__ __launch_bounds__(256) void vtrans_kernel(const unsigned short* __restrict__ Vb,
                                                     unsigned short* __restrict__ Vt) {
  __shared__ __attribute__((aligned(16))) unsigned short tile[64][72];
  const int bh = blockIdx.y;
  const int s0 = blockIdx.x * 64;
  const int tid = threadIdx.x;
  const unsigned short* src = Vb + (size_t)bh * S_ * HD + (size_t)s0 * HD;
#pragma unroll
  for (int i = 0; i < 2; i++) {
    int c = tid + i * 256;
    int r = c >> 3;            // s-local
    int cc = (c & 7) * 8;      // hd
    *(uint4*)(&tile[r][cc]) = *(const uint4*)(src + r * HD + cc);
  }
  __syncthreads();
  unsigned short* dst = Vt + (size_t)bh * HD * S_ + s0;
#pragma unroll
  for (int i = 0; i < 2; i++) {
    int c = tid + i * 256;
    int r = c >> 3;            // hd
    int cc = (c & 7) * 8;      // s-local
    union { unsigned short u[8]; uint4 v; } t;
#pragma unroll
    for (int j = 0; j < 8; j++) t.u[j] = tile[cc + j][r];
    *(uint4*)(dst + (size_t)r * S_ + cc) = t.v;
  }
}

// ---------- GEMM: C = A[M][K] * Bt[N][K]^T, bf16 in, fp32 acc ----------
// MODE 0: write bf16 scattered to [B,H,S,HD] head-major (QKV projections)
// MODE 1: write fp32 row-major + bias (output projection)
template <int MODE>
__global__ __launch_bounds__(256) void gemm_kernel(
    const unsigned short* __restrict__ A,
    const unsigned short* __restrict__ Bt,
    unsigned short* __restrict__ outB,
    float* __restrict__ outF,
    const float* __restrict__ bias,
    int M, int N, int K) {
  // stride 40 (=80B, 16B-aligned, 20 banks): frag b128 reads land 2-way (free)
  __shared__ __attribute__((aligned(16))) unsigned short Asm_[128 * 40];
  __shared__ __attribute__((aligned(16))) unsigned short Bsm_[128 * 40];
  const int tid = threadIdx.x;
  const int lane = tid & 63;
  const int w = tid >> 6;
  const int wm = w >> 1, wn = w & 1;
  const int quad = lane >> 4, l16 = lane & 15;
  const int m0 = blockIdx.x * 128;
  const int n0 = blockIdx.y * 128;

  const int crow = tid >> 2;        // 0..63
  const int ckk = (tid & 3) * 8;    // 0,8,16,24

  f32x4 acc[4][4] = {};

  for (int k0 = 0; k0 < K; k0 += 32) {
    uint4 av0 = *(const uint4*)(A + (size_t)(m0 + crow) * K + k0 + ckk);
    uint4 av1 = *(const uint4*)(A + (size_t)(m0 + 64 + crow) * K + k0 + ckk);
    uint4 bv0 = *(const uint4*)(Bt + (size_t)(n0 + crow) * K + k0 + ckk);
    uint4 bv1 = *(const uint4*)(Bt + (size_t)(n0 + 64 + crow) * K + k0 + ckk);
    __syncthreads();
    *(uint4*)(Asm_ + crow * 40 + ckk) = av0;
    *(uint4*)(Asm_ + (64 + crow) * 40 + ckk) = av1;
    *(uint4*)(Bsm_ + crow * 40 + ckk) = bv0;
    *(uint4*)(Bsm_ + (64 + crow) * 40 + ckk) = bv1;
    __syncthreads();
    short8 af[4], bfr[4];
#pragma unroll
    for (int mi = 0; mi < 4; mi++)
      af[mi] = *(const short8*)(Asm_ + (wm * 64 + mi * 16 + l16) * 40 + quad * 8);
#pragma unroll
    for (int ni = 0; ni < 4; ni++)
      bfr[ni] = *(const short8*)(Bsm_ + (wn * 64 + ni * 16 + l16) * 40 + quad * 8);
#pragma unroll
    for (int mi = 0; mi < 4; mi++)
#pragma unroll
      for (int ni = 0; ni < 4; ni++)
        acc[mi][ni] = __builtin_amdgcn_mfma_f32_16x16x32_bf16(af[mi], bfr[ni], acc[mi][ni], 0, 0, 0);
  }

#pragma unroll
  for (int mi = 0; mi < 4; mi++) {
#pragma unroll
    for (int ni = 0; ni < 4; ni++) {
      const int col = n0 + wn * 64 + ni * 16 + l16;
      float bv = (MODE == 1) ? bias[col] : 0.f;
#pragma unroll
      for (int r = 0; r < 4; r++) {
        const int row = m0 + wm * 64 + mi * 16 + quad * 4 + r;  // C/D: row=quad*4+reg, col=lane&15
        if (MODE == 0) {
          int b = row >> 11, s = row & 2047;
          int h = col >> 6, hd = col & 63;
          outB[(((size_t)(b * NHD + h)) * S_ + s) * HD + hd] = f32_bf16(acc[mi][ni][r]);
        } else {
          outF[(size_t)row * N + col] = acc[mi][ni][r] + bv;
        }
      }
    }
  }
}

// ---------- flash attention, causal. Q-tile 128 (4 waves x 32 rows), K-tile 64 ----------
__global__ __launch_bounds__(256) void attn_kernel(
    const unsigned short* __restrict__ Q,
    const unsigned short* __restrict__ Kmat,
    const unsigned short* __restrict__ Vt,
    unsigned short* __restrict__ ctx) {
  __shared__ __attribute__((aligned(16))) unsigned short Qs[128 * 72];
  __shared__ __attribute__((aligned(16))) unsigned short Ks[64 * 72];
  __shared__ __attribute__((aligned(16))) unsigned short Vs[64 * 72];   // [hd][key]
  __shared__ __attribute__((aligned(16))) unsigned short Ps[128 * 72];  // [m][key]

  const int tid = threadIdx.x;
  const int lane = tid & 63;
  const int w = tid >> 6;
  const int quad = lane >> 4, l16 = lane & 15;
  const int bh = blockIdx.y;
  const int qBase = blockIdx.x * 128;

  const unsigned short* Qh = Q + (size_t)bh * S_ * HD;
  const unsigned short* Kh = Kmat + (size_t)bh * S_ * HD;
  const unsigned short* Vh = Vt + (size_t)bh * HD * S_;

#pragma unroll
  for (int i = 0; i < 4; i++) {
    int c = tid + i * 256;
    int r = c >> 3, cc = (c & 7) * 8;
    *(uint4*)(Qs + r * 72 + cc) = *(const uint4*)(Qh + (size_t)(qBase + r) * HD + cc);
  }

  float mst[8], lst[8];
#pragma unroll
  for (int i = 0; i < 8; i++) { mst[i] = -__builtin_inff(); lst[i] = 0.f; }
  f32x4 oacc[2][4] = {};

  const int nt = 2 * blockIdx.x + 2;
  for (int kt = 0; kt < nt; kt++) {
    const int k0 = kt * 64;
    uint4 kv[2], vv[2];
#pragma unroll
    for (int i = 0; i < 2; i++) {
      int c = tid + i * 256;
      int r = c >> 3, cc = (c & 7) * 8;
      kv[i] = *(const uint4*)(Kh + (size_t)(k0 + r) * HD + cc);
      vv[i] = *(const uint4*)(Vh + (size_t)r * S_ + k0 + cc);
    }
    __syncthreads();   // prior iter's LDS reads complete
#pragma unroll
    for (int i = 0; i < 2; i++) {
      int c = tid + i * 256;
      int r = c >> 3, cc = (c & 7) * 8;
      *(uint4*)(Ks + r * 72 + cc) = kv[i];
      *(uint4*)(Vs + r * 72 + cc) = vv[i];
    }
    __syncthreads();   // K/V tiles visible

    // S = Q K^T : per wave 32(m) x 64(n)
    f32x4 sacc[2][4] = {};
#pragma unroll
    for (int ks = 0; ks < 2; ks++) {
      short8 af[2], bfr[4];
#pragma unroll
      for (int mi = 0; mi < 2; mi++)
        af[mi] = *(const short8*)(Qs + (w * 32 + mi * 16 + l16) * 72 + ks * 32 + quad * 8);
#pragma unroll
      for (int ni = 0; ni < 4; ni++)
        bfr[ni] = *(const short8*)(Ks + (ni * 16 + l16) * 72 + ks * 32 + quad * 8);
#pragma unroll
      for (int mi = 0; mi < 2; mi++)
#pragma unroll
        for (int ni = 0; ni < 4; ni++)
          sacc[mi][ni] = __builtin_amdgcn_mfma_f32_16x16x32_bf16(af[mi], bfr[ni], sacc[mi][ni], 0, 0, 0);
    }

    const bool need_mask = (kt >= nt - 2);
#pragma unroll
    for (int mi = 0; mi < 2; mi++) {
#pragma unroll
      for (int r = 0; r < 4; r++) {
        const int qg = qBase + w * 32 + mi * 16 + quad * 4 + r;
        float rm = -__builtin_inff();
#pragma unroll
        for (int ni = 0; ni < 4; ni++) {
          float sv = sacc[mi][ni][r] * 0.125f;   // 1/sqrt(64)
          if (need_mask && (k0 + ni * 16 + l16) > qg) sv = -__builtin_inff();
          sacc[mi][ni][r] = sv;
          rm = fmaxf(rm, sv);
        }
        rm = fmaxf(rm, __shfl_xor(rm, 1));
        rm = fmaxf(rm, __shfl_xor(rm, 2));
        rm = fmaxf(rm, __shfl_xor(rm, 4));
        rm = fmaxf(rm, __shfl_xor(rm, 8));
        const int si = mi * 4 + r;
        float mnew = fmaxf(mst[si], rm);
        float alpha = __expf(mst[si] - mnew);    // exp(-inf)=0 on first tile
        mst[si] = mnew;
        float rs = 0.f;
#pragma unroll
        for (int ni = 0; ni < 4; ni++) {
          float p = __expf(sacc[mi][ni][r] - mnew);
          sacc[mi][ni][r] = p;
          rs += p;
        }
        rs += __shfl_xor(rs, 1);
        rs += __shfl_xor(rs, 2);
        rs += __shfl_xor(rs, 4);
        rs += __shfl_xor(rs, 8);
        lst[si] = lst[si] * alpha + rs;
#pragma unroll
        for (int nh = 0; nh < 4; nh++) oacc[mi][nh][r] *= alpha;
      }
    }

    // P (C/D layout) -> LDS -> A-operand layout. Rows are wave-local: no barrier needed.
#pragma unroll
    for (int mi = 0; mi < 2; mi++)
#pragma unroll
      for (int ni = 0; ni < 4; ni++)
#pragma unroll
        for (int r = 0; r < 4; r++)
          Ps[(w * 32 + mi * 16 + quad * 4 + r) * 72 + ni * 16 + l16] = f32_bf16(sacc[mi][ni][r]);

    // O += P V
#pragma unroll
    for (int ks = 0; ks < 2; ks++) {
      short8 pf[2], vf[4];
#pragma unroll
      for (int mi = 0; mi < 2; mi++)
        pf[mi] = *(const short8*)(Ps + (w * 32 + mi * 16 + l16) * 72 + ks * 32 + quad * 8);
#pragma unroll
      for (int nh = 0; nh < 4; nh++)
        vf[nh] = *(const short8*)(Vs + (nh * 16 + l16) * 72 + ks * 32 + quad * 8);
#pragma unroll
      for (int mi = 0; mi < 2; mi++)
#pragma unroll
        for (int nh = 0; nh < 4; nh++)
          oacc[mi][nh] = __builtin_amdgcn_mfma_f32_16x16x32_bf16(pf[mi], vf[nh], oacc[mi][nh], 0, 0, 0);
    }
  }

  const int b = bh >> 4, h = bh & 15;
#pragma unroll
  for (int mi = 0; mi < 2; mi++)
#pragma unroll
    for (int nh = 0; nh < 4; nh++)
#pragma unroll
      for (int r = 0; r < 4; r++) {
        int s = qBase + w * 32 + mi * 16 + quad * 4 + r;
        int col = h * HD + nh * 16 + l16;
        float v = oacc[mi][nh][r] / lst[mi * 4 + r];
        ctx[((size_t)(b * S_ + s)) * DOUT + col] = f32_bf16(v);
      }
}

extern "C" void kernel_launch(void* const* d_in, const int* in_sizes, int n_in,
                              void* d_out, int out_size, void* d_ws, size_t ws_size,
                              hipStream_t stream) {
  const float* x  = (const float*)d_in[0];
  const float* Wq = (const float*)d_in[1];
  const float* Wk = (const float*)d_in[2];
  const float* Wv = (const float*)d_in[3];
  const float* Wo = (const float*)d_in[4];
  const float* bo = (const float*)d_in[5];
  float* out = (float*)d_out;
  char* ws = (char*)d_ws;

  const size_t MB = 1024 * 1024;
  unsigned short* Wqt = (unsigned short*)(ws + 0 * MB);   // [N][K] bf16, 2 MB each
  unsigned short* Wkt = (unsigned short*)(ws + 2 * MB);
  unsigned short* Wvt = (unsigned short*)(ws + 4 * MB);
  unsigned short* Wot = (unsigned short*)(ws + 6 * MB);
  unsigned short* xb  = (unsigned short*)(ws + 8 * MB);   // 16 MB; reused as ctx after QKV
  unsigned short* Qb  = (unsigned short*)(ws + 24 * MB);  // [B,H,S,HD] 16 MB
  unsigned short* Kb  = (unsigned short*)(ws + 40 * MB);
  unsigned short* Vb  = (unsigned short*)(ws + 56 * MB);
  unsigned short* Vtb = (unsigned short*)(ws + 72 * MB);  // [B,H,HD,S] 16 MB
  unsigned short* ctxb = xb;                              // alias: xb dead after QKV GEMMs

  cvt_kernel<<<8192, 256, 0, stream>>>(x, xb, 2097152);
  wtrans_kernel<<<dim3(16, 16), 256, 0, stream>>>(Wq, Wqt);
  wtrans_kernel<<<dim3(16, 16), 256, 0, stream>>>(Wk, Wkt);
  wtrans_kernel<<<dim3(16, 16), 256, 0, stream>>>(Wv, Wvt);
  wtrans_kernel<<<dim3(16, 16), 256, 0, stream>>>(Wo, Wot);
  gemm_kernel<0><<<dim3(64, 8), 256, 0, stream>>>(xb, Wqt, Qb, nullptr, nullptr, 8192, 1024, 1024);
  gemm_kernel<0><<<dim3(64, 8), 256, 0, stream>>>(xb, Wkt, Kb, nullptr, nullptr, 8192, 1024, 1024);
  gemm_kernel<0><<<dim3(64, 8), 256, 0, stream>>>(xb, Wvt, Vb, nullptr, nullptr, 8192, 1024, 1024);
  vtrans_kernel<<<dim3(32, 64), 256, 0, stream>>>(Vb, Vtb);
  attn_kernel<<<dim3(16, 64), 256, 0, stream>>>(Qb, Kb, Vtb, ctxb);
  gemm_kernel<1><<<dim3(64, 8), 256, 0, stream>>>(ctxb, Wot, nullptr, out, bo, 8192, 1024, 1024);
}

// Round 2
// 375.768 us; speedup vs baseline: 1.2820x; 1.2820x over previous
//
#include <hip/hip_runtime.h>
#include <stdint.h>

#define B_   4
#define S_   2048
#define DI   1024
#define DOUT 1024
#define NHD  16
#define HD   64

typedef __attribute__((ext_vector_type(8))) short short8;
typedef __attribute__((ext_vector_type(4))) float f32x4;
typedef __attribute__((ext_vector_type(16))) float f32x16;

__device__ __forceinline__ unsigned short f32_bf16(float f) {
  union { float f; unsigned u; } v; v.f = f;
  unsigned r = v.u + 0x7FFFu + ((v.u >> 16) & 1u);   // RNE
  return (unsigned short)(r >> 16);
}

// round-half-up bf16 pack of two floats -> uint32 (lo=a, hi=b)
__device__ __forceinline__ unsigned pack_bf16x2(float a, float b) {
  union { float f; unsigned u; } x, y; x.f = a; y.f = b;
  return ((y.u + 0x8000u) & 0xFFFF0000u) | ((x.u + 0x8000u) >> 16);
}

// ---------- elementwise fp32 -> bf16 ----------
__global__ __launch_bounds__(256) void cvt_kernel(const float* __restrict__ src,
                                                  unsigned short* __restrict__ dst, int n4) {
  int i = blockIdx.x * blockDim.x + threadIdx.x;
  if (i < n4) {
    float4 v = ((const float4*)src)[i];
    ushort4 o;
    o.x = f32_bf16(v.x); o.y = f32_bf16(v.y); o.z = f32_bf16(v.z); o.w = f32_bf16(v.w);
    ((ushort4*)dst)[i] = o;
  }
}

// ---------- weight transpose+convert: W[k][n] f32 -> Wt[n][k] bf16 ----------
__global__ __launch_bounds__(256) void wtrans_kernel(const float* __restrict__ W,
                                                     unsigned short* __restrict__ Wt) {
  __shared__ __attribute__((aligned(16))) float tile[64][65];
  const int k0 = blockIdx.y * 64;
  const int n0 = blockIdx.x * 64;
  const int tid = threadIdx.x;
#pragma unroll
  for (int i = 0; i < 4; i++) {
    int c = tid + i * 256;
    int r = c >> 4;
    int cc = (c & 15) * 4;
    float4 v = *(const float4*)(W + (size_t)(k0 + r) * DOUT + n0 + cc);
    tile[r][cc] = v.x; tile[r][cc + 1] = v.y; tile[r][cc + 2] = v.z; tile[r][cc + 3] = v.w;
  }
  __syncthreads();
#pragma unroll
  for (int i = 0; i < 4; i++) {
    int c = tid + i * 256;
    int r = c >> 4;
    int cc = (c & 15) * 4;
    ushort4 o;
    o.x = f32_bf16(tile[cc + 0][r]);
    o.y = f32_bf16(tile[cc + 1][r]);
    o.z = f32_bf16(tile[cc + 2][r]);
    o.w = f32_bf16(tile[cc + 3][r]);
    *(ushort4*)(Wt + (size_t)(n0 + r) * DI + k0 + cc) = o;
  }
}

// ---------- V transpose: Vb[bh][s][hd] -> Vt[bh][hd][s] (bf16) ----------
__global__ __launch_bounds__(256) void vtrans_kernel(const unsigned short* __restrict__ Vb,
                                                     unsigned short* __restrict__ Vt) {
  __shared__ __attribute__((aligned(16))) unsigned short tile[64][72];
  const int bh = blockIdx.y;
  const int s0 = blockIdx.x * 64;
  const int tid = threadIdx.x;
  const unsigned short* src = Vb + (size_t)bh * S_ * HD + (size_t)s0 * HD;
#pragma unroll
  for (int i = 0; i < 2; i++) {
    int c = tid + i * 256;
    int r = c >> 3;
    int cc = (c & 7) * 8;
    *(uint4*)(&tile[r][cc]) = *(const uint4*)(src + r * HD + cc);
  }
  __syncthreads();
  unsigned short* dst = Vt + (size_t)bh * HD * S_ + s0;
#pragma unroll
  for (int i = 0; i < 2; i++) {
    int c = tid + i * 256;
    int r = c >> 3;
    int cc = (c & 7) * 8;
    union { unsigned short u[8]; uint4 v; } t;
#pragma unroll
    for (int j = 0; j < 8; j++) t.u[j] = tile[cc + j][r];
    *(uint4*)(dst + (size_t)r * S_ + cc) = t.v;
  }
}

// ---------- GEMM: C = A[M][K] * Bt[N][K]^T, bf16 in, fp32 acc ----------
template <int MODE>
__global__ __launch_bounds__(256) void gemm_kernel(
    const unsigned short* __restrict__ A,
    const unsigned short* __restrict__ Bt,
    unsigned short* __restrict__ outB,
    float* __restrict__ outF,
    const float* __restrict__ bias,
    int M, int N, int K) {
  __shared__ __attribute__((aligned(16))) unsigned short Asm_[128 * 40];
  __shared__ __attribute__((aligned(16))) unsigned short Bsm_[128 * 40];
  const int tid = threadIdx.x;
  const int lane = tid & 63;
  const int w = tid >> 6;
  const int wm = w >> 1, wn = w & 1;
  const int quad = lane >> 4, l16 = lane & 15;
  const int m0 = blockIdx.x * 128;
  const int n0 = blockIdx.y * 128;

  const int crow = tid >> 2;
  const int ckk = (tid & 3) * 8;

  f32x4 acc[4][4] = {};

  for (int k0 = 0; k0 < K; k0 += 32) {
    uint4 av0 = *(const uint4*)(A + (size_t)(m0 + crow) * K + k0 + ckk);
    uint4 av1 = *(const uint4*)(A + (size_t)(m0 + 64 + crow) * K + k0 + ckk);
    uint4 bv0 = *(const uint4*)(Bt + (size_t)(n0 + crow) * K + k0 + ckk);
    uint4 bv1 = *(const uint4*)(Bt + (size_t)(n0 + 64 + crow) * K + k0 + ckk);
    __syncthreads();
    *(uint4*)(Asm_ + crow * 40 + ckk) = av0;
    *(uint4*)(Asm_ + (64 + crow) * 40 + ckk) = av1;
    *(uint4*)(Bsm_ + crow * 40 + ckk) = bv0;
    *(uint4*)(Bsm_ + (64 + crow) * 40 + ckk) = bv1;
    __syncthreads();
    short8 af[4], bfr[4];
#pragma unroll
    for (int mi = 0; mi < 4; mi++)
      af[mi] = *(const short8*)(Asm_ + (wm * 64 + mi * 16 + l16) * 40 + quad * 8);
#pragma unroll
    for (int ni = 0; ni < 4; ni++)
      bfr[ni] = *(const short8*)(Bsm_ + (wn * 64 + ni * 16 + l16) * 40 + quad * 8);
#pragma unroll
    for (int mi = 0; mi < 4; mi++)
#pragma unroll
      for (int ni = 0; ni < 4; ni++)
        acc[mi][ni] = __builtin_amdgcn_mfma_f32_16x16x32_bf16(af[mi], bfr[ni], acc[mi][ni], 0, 0, 0);
  }

#pragma unroll
  for (int mi = 0; mi < 4; mi++) {
#pragma unroll
    for (int ni = 0; ni < 4; ni++) {
      const int col = n0 + wn * 64 + ni * 16 + l16;
      float bv = (MODE == 1) ? bias[col] : 0.f;
#pragma unroll
      for (int r = 0; r < 4; r++) {
        const int row = m0 + wm * 64 + mi * 16 + quad * 4 + r;
        if (MODE == 0) {
          int b = row >> 11, s = row & 2047;
          int h = col >> 6, hd = col & 63;
          outB[(((size_t)(b * NHD + h)) * S_ + s) * HD + hd] = f32_bf16(acc[mi][ni][r]);
        } else {
          outF[(size_t)row * N + col] = acc[mi][ni][r] + bv;
        }
      }
    }
  }
}

// ---------- flash attention, causal — S^T formulation ----------
// One wave owns one (bh, 32-qrow chunk) task. No __syncthreads at all:
// all LDS regions are wave-private. K/V fragments read direct from global.
// S^T = K*Q^T via mfma_32x32x16 (C/D: col=lane&31=qrow, row=key — HW-verified
// layout), softmax per-lane + one shfl_xor(32); P packed b64 into PsT[qrow][key];
// O^T = V^T * P^T; epilogue transposes via Os for coalesced 16B stores.
__global__ __launch_bounds__(256, 4) void attn_kernel(
    const unsigned short* __restrict__ Q,
    const unsigned short* __restrict__ Kmat,
    const unsigned short* __restrict__ Vt,
    unsigned short* __restrict__ ctx) {
  __shared__ __attribute__((aligned(16))) unsigned short PsT[128 * 72];
  __shared__ __attribute__((aligned(16))) unsigned short Os[128 * 72];

  const int tid = threadIdx.x;
  const int lane = tid & 63;
  const int w = tid >> 6;
  const int l32 = lane & 31;
  const int h = lane >> 5;      // half-wave select

  const int task = blockIdx.x * 4 + w;     // 4096 wave-tasks
  const int qc = 63 - (task >> 6);         // heavy chunks dispatched first (LPT)
  const int bh = task & 63;
  const int nt = (qc >> 1) + 1;            // # of 64-key tiles for this chunk

  const unsigned short* Qh = Q + (size_t)bh * S_ * HD;
  const unsigned short* Kh = Kmat + (size_t)bh * S_ * HD;
  const unsigned short* Vh = Vt + (size_t)bh * HD * S_;

  const int qrow = qc * 32 + l32;          // this lane's global q row

  // Q fragments (B-operand of S^T), hoisted for the whole task: 16 VGPRs
  short8 qf[4];
#pragma unroll
  for (int ks = 0; ks < 4; ks++)
    qf[ks] = *(const short8*)(Qh + (size_t)qrow * HD + ks * 16 + h * 8);

  f32x16 oacc[2] = {};
  float m_run = -__builtin_inff();
  float l_run = 0.f;

  unsigned short* myP = PsT + (size_t)(w * 32) * 72;
  const float scl = 0.18033688f;           // (1/sqrt(64)) * log2(e), exp2 domain

  for (int kt = 0; kt < nt; kt++) {
    const int k0 = kt * 64;

    // ---- S^T = K * Q^T : 64 keys x 32 qrows, 8 MFMAs ----
    f32x16 sacc[2] = {};
#pragma unroll
    for (int ks = 0; ks < 4; ks++) {
#pragma unroll
      for (int mi = 0; mi < 2; mi++) {
        short8 kf = *(const short8*)(Kh + (size_t)(k0 + mi * 32 + l32) * HD + ks * 16 + h * 8);
        sacc[mi] = __builtin_amdgcn_mfma_f32_32x32x16_bf16(kf, qf[ks], sacc[mi], 0, 0, 0);
      }
    }

    // ---- online softmax (log2 domain). C/D row = (e&3)+8*(e>>2)+4*h ----
    const bool diag = (kt == nt - 1);
    float vmax = -__builtin_inff();
#pragma unroll
    for (int mi = 0; mi < 2; mi++) {
#pragma unroll
      for (int e = 0; e < 16; e++) {
        float v = sacc[mi][e] * scl;
        if (diag) {
          int key = k0 + mi * 32 + (e & 3) + 8 * (e >> 2) + 4 * h;
          if (key > qrow) v = -__builtin_inff();
        }
        sacc[mi][e] = v;
        vmax = fmaxf(vmax, v);
      }
    }
    vmax = fmaxf(vmax, __shfl_xor(vmax, 32));
    const float mnew = fmaxf(m_run, vmax);
    const float alpha = exp2f(m_run - mnew);
    m_run = mnew;

    float rs = 0.f;
#pragma unroll
    for (int mi = 0; mi < 2; mi++) {
#pragma unroll
      for (int e = 0; e < 16; e++) {
        float p = exp2f(sacc[mi][e] - mnew);
        sacc[mi][e] = p;
        rs += p;
      }
    }
    rs += __shfl_xor(rs, 32);
    l_run = l_run * alpha + rs;
#pragma unroll
    for (int mi = 0; mi < 2; mi++) oacc[mi] *= alpha;

    // ---- P -> LDS PsT[qrow][key], packed b64 (keys mi*32+g*8+4h .. +3) ----
#pragma unroll
    for (int mi = 0; mi < 2; mi++) {
#pragma unroll
      for (int g = 0; g < 4; g++) {
        uint2 pk;
        pk.x = pack_bf16x2(sacc[mi][4 * g + 0], sacc[mi][4 * g + 1]);
        pk.y = pack_bf16x2(sacc[mi][4 * g + 2], sacc[mi][4 * g + 3]);
        *(uint2*)(myP + l32 * 72 + mi * 32 + g * 8 + h * 4) = pk;
      }
    }

    // ---- O^T += V^T * P^T : 8 MFMAs ----
#pragma unroll
    for (int ks2 = 0; ks2 < 4; ks2++) {
      short8 pf = *(const short8*)(myP + l32 * 72 + ks2 * 16 + h * 8);
#pragma unroll
      for (int mi2 = 0; mi2 < 2; mi2++) {
        short8 vf = *(const short8*)(Vh + (size_t)(mi2 * 32 + l32) * S_ + k0 + ks2 * 16 + h * 8);
        oacc[mi2] = __builtin_amdgcn_mfma_f32_32x32x16_bf16(vf, pf, oacc[mi2], 0, 0, 0);
      }
    }
  }

  // ---- epilogue: O^T / l -> Os[qrow][hd] -> coalesced global ----
  const float inv = 1.f / l_run;
  unsigned short* myO = Os + (size_t)(w * 32) * 72;
#pragma unroll
  for (int mi2 = 0; mi2 < 2; mi2++) {
#pragma unroll
    for (int g = 0; g < 4; g++) {
      uint2 pk;
      pk.x = pack_bf16x2(oacc[mi2][4 * g + 0] * inv, oacc[mi2][4 * g + 1] * inv);
      pk.y = pack_bf16x2(oacc[mi2][4 * g + 2] * inv, oacc[mi2][4 * g + 3] * inv);
      *(uint2*)(myO + l32 * 72 + mi2 * 32 + g * 8 + h * 4) = pk;
    }
  }
  const int b = bh >> 4, head = bh & 15;
#pragma unroll
  for (int p = 0; p < 4; p++) {
    int r = p * 8 + (lane >> 3);
    int c = (lane & 7) * 8;
    uint4 vv = *(const uint4*)(myO + r * 72 + c);
    *(uint4*)(ctx + ((size_t)(b * S_ + qc * 32 + r)) * DOUT + head * 64 + c) = vv;
  }
}

extern "C" void kernel_launch(void* const* d_in, const int* in_sizes, int n_in,
                              void* d_out, int out_size, void* d_ws, size_t ws_size,
                              hipStream_t stream) {
  const float* x  = (const float*)d_in[0];
  const float* Wq = (const float*)d_in[1];
  const float* Wk = (const float*)d_in[2];
  const float* Wv = (const float*)d_in[3];
  const float* Wo = (const float*)d_in[4];
  const float* bo = (const float*)d_in[5];
  float* out = (float*)d_out;
  char* ws = (char*)d_ws;

  const size_t MB = 1024 * 1024;
  unsigned short* Wqt = (unsigned short*)(ws + 0 * MB);
  unsigned short* Wkt = (unsigned short*)(ws + 2 * MB);
  unsigned short* Wvt = (unsigned short*)(ws + 4 * MB);
  unsigned short* Wot = (unsigned short*)(ws + 6 * MB);
  unsigned short* xb  = (unsigned short*)(ws + 8 * MB);
  unsigned short* Qb  = (unsigned short*)(ws + 24 * MB);
  unsigned short* Kb  = (unsigned short*)(ws + 40 * MB);
  unsigned short* Vb  = (unsigned short*)(ws + 56 * MB);
  unsigned short* Vtb = (unsigned short*)(ws + 72 * MB);
  unsigned short* ctxb = xb;   // xb dead after QKV GEMMs

  cvt_kernel<<<8192, 256, 0, stream>>>(x, xb, 2097152);
  wtrans_kernel<<<dim3(16, 16), 256, 0, stream>>>(Wq, Wqt);
  wtrans_kernel<<<dim3(16, 16), 256, 0, stream>>>(Wk, Wkt);
  wtrans_kernel<<<dim3(16, 16), 256, 0, stream>>>(Wv, Wvt);
  wtrans_kernel<<<dim3(16, 16), 256, 0, stream>>>(Wo, Wot);
  gemm_kernel<0><<<dim3(64, 8), 256, 0, stream>>>(xb, Wqt, Qb, nullptr, nullptr, 8192, 1024, 1024);
  gemm_kernel<0><<<dim3(64, 8), 256, 0, stream>>>(xb, Wkt, Kb, nullptr, nullptr, 8192, 1024, 1024);
  gemm_kernel<0><<<dim3(64, 8), 256, 0, stream>>>(xb, Wvt, Vb, nullptr, nullptr, 8192, 1024, 1024);
  vtrans_kernel<<<dim3(32, 64), 256, 0, stream>>>(Vb, Vtb);
  attn_kernel<<<1024, 256, 0, stream>>>(Qb, Kb, Vtb, ctxb);
  gemm_kernel<1><<<dim3(64, 8), 256, 0, stream>>>(ctxb, Wot, nullptr, out, bo, 8192, 1024, 1024);
}

// Round 3
// 357.272 us; speedup vs baseline: 1.3484x; 1.0518x over previous
//
#include <hip/hip_runtime.h>
#include <stdint.h>

#define B_   4
#define S_   2048
#define DI   1024
#define DOUT 1024
#define NHD  16
#define HD   64

typedef __attribute__((ext_vector_type(8))) short short8;
typedef __attribute__((ext_vector_type(4))) float f32x4;
typedef __attribute__((ext_vector_type(16))) float f32x16;

__device__ __forceinline__ unsigned short f32_bf16(float f) {
  union { float f; unsigned u; } v; v.f = f;
  unsigned r = v.u + 0x7FFFu + ((v.u >> 16) & 1u);   // RNE
  return (unsigned short)(r >> 16);
}

// round-half-up bf16 pack of two floats -> uint32 (lo=a, hi=b)
__device__ __forceinline__ unsigned pack_bf16x2(float a, float b) {
  union { float f; unsigned u; } x, y; x.f = a; y.f = b;
  return ((y.u + 0x8000u) & 0xFFFF0000u) | ((x.u + 0x8000u) >> 16);
}

// async 16B global->LDS (dst must be wave-uniform; HW adds lane*16)
__device__ __forceinline__ void gl_lds16(const void* g, void* s) {
  __builtin_amdgcn_global_load_lds(
      (const __attribute__((address_space(1))) unsigned int*)g,
      (__attribute__((address_space(3))) unsigned int*)s, 16, 0, 0);
}

// ---------- elementwise fp32 -> bf16 ----------
__global__ __launch_bounds__(256) void cvt_kernel(const float* __restrict__ src,
                                                  unsigned short* __restrict__ dst, int n4) {
  int i = blockIdx.x * blockDim.x + threadIdx.x;
  if (i < n4) {
    float4 v = ((const float4*)src)[i];
    ushort4 o;
    o.x = f32_bf16(v.x); o.y = f32_bf16(v.y); o.z = f32_bf16(v.z); o.w = f32_bf16(v.w);
    ((ushort4*)dst)[i] = o;
  }
}

// ---------- weight transpose+convert: W[k][n] f32 -> Wt[n][k] bf16 ----------
__global__ __launch_bounds__(256) void wtrans_kernel(const float* __restrict__ W,
                                                     unsigned short* __restrict__ Wt) {
  __shared__ __attribute__((aligned(16))) float tile[64][65];
  const int k0 = blockIdx.y * 64;
  const int n0 = blockIdx.x * 64;
  const int tid = threadIdx.x;
#pragma unroll
  for (int i = 0; i < 4; i++) {
    int c = tid + i * 256;
    int r = c >> 4;
    int cc = (c & 15) * 4;
    float4 v = *(const float4*)(W + (size_t)(k0 + r) * DOUT + n0 + cc);
    tile[r][cc] = v.x; tile[r][cc + 1] = v.y; tile[r][cc + 2] = v.z; tile[r][cc + 3] = v.w;
  }
  __syncthreads();
#pragma unroll
  for (int i = 0; i < 4; i++) {
    int c = tid + i * 256;
    int r = c >> 4;
    int cc = (c & 15) * 4;
    ushort4 o;
    o.x = f32_bf16(tile[cc + 0][r]);
    o.y = f32_bf16(tile[cc + 1][r]);
    o.z = f32_bf16(tile[cc + 2][r]);
    o.w = f32_bf16(tile[cc + 3][r]);
    *(ushort4*)(Wt + (size_t)(n0 + r) * DI + k0 + cc) = o;
  }
}

// ---------- V transpose: Vb[bh][s][hd] -> Vt[bh][hd][s] (bf16) ----------
__global__ __launch_bounds__(256) void vtrans_kernel(const unsigned short* __restrict__ Vb,
                                                     unsigned short* __restrict__ Vt) {
  __shared__ __attribute__((aligned(16))) unsigned short tile[64][72];
  const int bh = blockIdx.y;
  const int s0 = blockIdx.x * 64;
  const int tid = threadIdx.x;
  const unsigned short* src = Vb + (size_t)bh * S_ * HD + (size_t)s0 * HD;
#pragma unroll
  for (int i = 0; i < 2; i++) {
    int c = tid + i * 256;
    int r = c >> 3;
    int cc = (c & 7) * 8;
    *(uint4*)(&tile[r][cc]) = *(const uint4*)(src + r * HD + cc);
  }
  __syncthreads();
  unsigned short* dst = Vt + (size_t)bh * HD * S_ + s0;
#pragma unroll
  for (int i = 0; i < 2; i++) {
    int c = tid + i * 256;
    int r = c >> 3;
    int cc = (c & 7) * 8;
    union { unsigned short u[8]; uint4 v; } t;
#pragma unroll
    for (int j = 0; j < 8; j++) t.u[j] = tile[cc + j][r];
    *(uint4*)(dst + (size_t)r * S_ + cc) = t.v;
  }
}

// ---------- GEMM (m97 recipe): C = A[M][K] * Bt[N][K]^T, global_load_lds staging ----------
template <int MODE>
__global__ __launch_bounds__(256) void gemm_kernel(
    const unsigned short* __restrict__ A,
    const unsigned short* __restrict__ Bt,
    unsigned short* __restrict__ outB,
    float* __restrict__ outF,
    const float* __restrict__ bias,
    int M, int N, int K) {
  __shared__ __attribute__((aligned(16))) unsigned short Asm_[128 * 32];  // unpadded!
  __shared__ __attribute__((aligned(16))) unsigned short Bsm_[128 * 32];
  const int tid = threadIdx.x;
  const int lane = tid & 63;
  const int w = tid >> 6;
  const int wm = w >> 1, wn = w & 1;
  const int quad = lane >> 4, l16 = lane & 15;
  const int m0 = blockIdx.x * 128;
  const int n0 = blockIdx.y * 128;

  // staging: wave w covers rows w*32..w*32+31 in two 16-row calls.
  // lane l -> row offset (l>>2), col (l&3)*8; LDS dst uniform, HW adds lane*16.
  const int lr = lane >> 2;
  const int lc8 = (lane & 3) * 8;
  const unsigned short* gA0 = A + (size_t)(m0 + w * 32 + lr) * K + lc8;
  const unsigned short* gA1 = gA0 + (size_t)16 * K;
  const unsigned short* gB0 = Bt + (size_t)(n0 + w * 32 + lr) * K + lc8;
  const unsigned short* gB1 = gB0 + (size_t)16 * K;
  unsigned short* sA0 = Asm_ + (w * 2 + 0) * 512;
  unsigned short* sA1 = Asm_ + (w * 2 + 1) * 512;
  unsigned short* sB0 = Bsm_ + (w * 2 + 0) * 512;
  unsigned short* sB1 = Bsm_ + (w * 2 + 1) * 512;

  f32x4 acc[4][4] = {};

  for (int k0 = 0; k0 < K; k0 += 32) {
    __syncthreads();                 // prev iter's frag reads done
    gl_lds16(gA0 + k0, sA0);
    gl_lds16(gA1 + k0, sA1);
    gl_lds16(gB0 + k0, sB0);
    gl_lds16(gB1 + k0, sB1);
    __syncthreads();                 // vmcnt(0) drain -> tiles visible
    short8 af[4], bfr[4];
#pragma unroll
    for (int mi = 0; mi < 4; mi++)
      af[mi] = *(const short8*)(Asm_ + (wm * 64 + mi * 16 + l16) * 32 + quad * 8);
#pragma unroll
    for (int ni = 0; ni < 4; ni++)
      bfr[ni] = *(const short8*)(Bsm_ + (wn * 64 + ni * 16 + l16) * 32 + quad * 8);
#pragma unroll
    for (int mi = 0; mi < 4; mi++)
#pragma unroll
      for (int ni = 0; ni < 4; ni++)
        acc[mi][ni] = __builtin_amdgcn_mfma_f32_16x16x32_bf16(af[mi], bfr[ni], acc[mi][ni], 0, 0, 0);
  }

#pragma unroll
  for (int mi = 0; mi < 4; mi++) {
#pragma unroll
    for (int ni = 0; ni < 4; ni++) {
      const int col = n0 + wn * 64 + ni * 16 + l16;
      float bv = (MODE == 1) ? bias[col] : 0.f;
#pragma unroll
      for (int r = 0; r < 4; r++) {
        const int row = m0 + wm * 64 + mi * 16 + quad * 4 + r;
        if (MODE == 0) {
          int b = row >> 11, s = row & 2047;
          int h = col >> 6, hd = col & 63;
          outB[(((size_t)(b * NHD + h)) * S_ + s) * HD + hd] = f32_bf16(acc[mi][ni][r]);
        } else {
          outF[(size_t)row * N + col] = acc[mi][ni][r] + bv;
        }
      }
    }
  }
}

// ---------- flash attention, causal — S^T formulation, L1-sharing blocks ----------
// 512-thread block = 8 waves, ALL same bh, 8 consecutive qc (near-lockstep kt
// loop -> K/V tiles hit L1 ~8x). No __syncthreads; LDS wave-private.
__global__ __launch_bounds__(512, 2) void attn_kernel(
    const unsigned short* __restrict__ Q,
    const unsigned short* __restrict__ Kmat,
    const unsigned short* __restrict__ Vt,
    unsigned short* __restrict__ ctx) {
  __shared__ __attribute__((aligned(16))) unsigned short PsT[256 * 72];  // 8 waves x 32 rows

  const int tid = threadIdx.x;
  const int lane = tid & 63;
  const int w = tid >> 6;          // 0..7
  const int l32 = lane & 31;
  const int h = lane >> 5;

  const int bh = blockIdx.x & 63;
  const int qg = blockIdx.x >> 6;          // 0..7, heavy-first
  const int qc = 63 - (qg * 8 + w);
  const int nt = (qc >> 1) + 1;

  const unsigned short* Qh = Q + (size_t)bh * S_ * HD;
  const unsigned short* Kh = Kmat + (size_t)bh * S_ * HD;
  const unsigned short* Vh = Vt + (size_t)bh * HD * S_;

  const int qrow = qc * 32 + l32;

  short8 qf[4];
#pragma unroll
  for (int ks = 0; ks < 4; ks++)
    qf[ks] = *(const short8*)(Qh + (size_t)qrow * HD + ks * 16 + h * 8);

  f32x16 oacc[2] = {};
  float m_run = -__builtin_inff();
  float l_run = 0.f;

  unsigned short* myP = PsT + (size_t)(w * 32) * 72;
  const float scl = 0.18033688f;   // (1/sqrt(64)) * log2(e)

  for (int kt = 0; kt < nt; kt++) {
    const int k0 = kt * 64;

    // ---- V prefetch (independent of S; latency hides behind MFMA+softmax) ----
    short8 vf[4][2];
#pragma unroll
    for (int ks2 = 0; ks2 < 4; ks2++)
#pragma unroll
      for (int mi2 = 0; mi2 < 2; mi2++)
        vf[ks2][mi2] = *(const short8*)(Vh + (size_t)(mi2 * 32 + l32) * S_ + k0 + ks2 * 16 + h * 8);

    // ---- S^T = K * Q^T ----
    f32x16 sacc[2] = {};
#pragma unroll
    for (int ks = 0; ks < 4; ks++) {
#pragma unroll
      for (int mi = 0; mi < 2; mi++) {
        short8 kf = *(const short8*)(Kh + (size_t)(k0 + mi * 32 + l32) * HD + ks * 16 + h * 8);
        sacc[mi] = __builtin_amdgcn_mfma_f32_32x32x16_bf16(kf, qf[ks], sacc[mi], 0, 0, 0);
      }
    }

    // ---- online softmax: max on RAW scores, fma+exp2 ----
    if (kt == nt - 1) {   // diagonal tile: mask
#pragma unroll
      for (int mi = 0; mi < 2; mi++)
#pragma unroll
        for (int e = 0; e < 16; e++) {
          int key = k0 + mi * 32 + (e & 3) + 8 * (e >> 2) + 4 * h;
          if (key > qrow) sacc[mi][e] = -__builtin_inff();
        }
    }
    float vmax = -__builtin_inff();
#pragma unroll
    for (int mi = 0; mi < 2; mi++)
#pragma unroll
      for (int e = 0; e < 16; e++) vmax = fmaxf(vmax, sacc[mi][e]);
    vmax = fmaxf(vmax, __shfl_xor(vmax, 32));
    const float mnew = fmaxf(m_run, vmax * scl);
    const float alpha = exp2f(m_run - mnew);
    m_run = mnew;

    float rs = 0.f;
#pragma unroll
    for (int mi = 0; mi < 2; mi++)
#pragma unroll
      for (int e = 0; e < 16; e++) {
        float p = exp2f(fmaf(sacc[mi][e], scl, -mnew));
        sacc[mi][e] = p;
        rs += p;
      }
    rs += __shfl_xor(rs, 32);
    l_run = l_run * alpha + rs;
#pragma unroll
    for (int mi = 0; mi < 2; mi++) oacc[mi] *= alpha;

    // ---- P -> LDS PsT[qrow][key] packed b64 ----
#pragma unroll
    for (int mi = 0; mi < 2; mi++)
#pragma unroll
      for (int g = 0; g < 4; g++) {
        uint2 pk;
        pk.x = pack_bf16x2(sacc[mi][4 * g + 0], sacc[mi][4 * g + 1]);
        pk.y = pack_bf16x2(sacc[mi][4 * g + 2], sacc[mi][4 * g + 3]);
        *(uint2*)(myP + l32 * 72 + mi * 32 + g * 8 + h * 4) = pk;
      }

    // ---- O^T += V^T * P^T ----
#pragma unroll
    for (int ks2 = 0; ks2 < 4; ks2++) {
      short8 pf = *(const short8*)(myP + l32 * 72 + ks2 * 16 + h * 8);
#pragma unroll
      for (int mi2 = 0; mi2 < 2; mi2++)
        oacc[mi2] = __builtin_amdgcn_mfma_f32_32x32x16_bf16(vf[ks2][mi2], pf, oacc[mi2], 0, 0, 0);
    }
  }

  // ---- epilogue: O^T / l -> LDS (reuse myP) -> coalesced 16B stores ----
  const float inv = 1.f / l_run;
#pragma unroll
  for (int mi2 = 0; mi2 < 2; mi2++)
#pragma unroll
    for (int g = 0; g < 4; g++) {
      uint2 pk;
      pk.x = pack_bf16x2(oacc[mi2][4 * g + 0] * inv, oacc[mi2][4 * g + 1] * inv);
      pk.y = pack_bf16x2(oacc[mi2][4 * g + 2] * inv, oacc[mi2][4 * g + 3] * inv);
      *(uint2*)(myP + l32 * 72 + mi2 * 32 + g * 8 + h * 4) = pk;
    }
  const int b = bh >> 4, head = bh & 15;
#pragma unroll
  for (int p = 0; p < 4; p++) {
    int r = p * 8 + (lane >> 3);
    int c = (lane & 7) * 8;
    uint4 vv = *(const uint4*)(myP + r * 72 + c);
    *(uint4*)(ctx + ((size_t)(b * S_ + qc * 32 + r)) * DOUT + head * 64 + c) = vv;
  }
}

extern "C" void kernel_launch(void* const* d_in, const int* in_sizes, int n_in,
                              void* d_out, int out_size, void* d_ws, size_t ws_size,
                              hipStream_t stream) {
  const float* x  = (const float*)d_in[0];
  const float* Wq = (const float*)d_in[1];
  const float* Wk = (const float*)d_in[2];
  const float* Wv = (const float*)d_in[3];
  const float* Wo = (const float*)d_in[4];
  const float* bo = (const float*)d_in[5];
  float* out = (float*)d_out;
  char* ws = (char*)d_ws;

  const size_t MB = 1024 * 1024;
  unsigned short* Wqt = (unsigned short*)(ws + 0 * MB);
  unsigned short* Wkt = (unsigned short*)(ws + 2 * MB);
  unsigned short* Wvt = (unsigned short*)(ws + 4 * MB);
  unsigned short* Wot = (unsigned short*)(ws + 6 * MB);
  unsigned short* xb  = (unsigned short*)(ws + 8 * MB);
  unsigned short* Qb  = (unsigned short*)(ws + 24 * MB);
  unsigned short* Kb  = (unsigned short*)(ws + 40 * MB);
  unsigned short* Vb  = (unsigned short*)(ws + 56 * MB);
  unsigned short* Vtb = (unsigned short*)(ws + 72 * MB);
  unsigned short* ctxb = xb;   // xb dead after QKV GEMMs

  cvt_kernel<<<8192, 256, 0, stream>>>(x, xb, 2097152);
  wtrans_kernel<<<dim3(16, 16), 256, 0, stream>>>(Wq, Wqt);
  wtrans_kernel<<<dim3(16, 16), 256, 0, stream>>>(Wk, Wkt);
  wtrans_kernel<<<dim3(16, 16), 256, 0, stream>>>(Wv, Wvt);
  wtrans_kernel<<<dim3(16, 16), 256, 0, stream>>>(Wo, Wot);
  gemm_kernel<0><<<dim3(64, 8), 256, 0, stream>>>(xb, Wqt, Qb, nullptr, nullptr, 8192, 1024, 1024);
  gemm_kernel<0><<<dim3(64, 8), 256, 0, stream>>>(xb, Wkt, Kb, nullptr, nullptr, 8192, 1024, 1024);
  gemm_kernel<0><<<dim3(64, 8), 256, 0, stream>>>(xb, Wvt, Vb, nullptr, nullptr, 8192, 1024, 1024);
  vtrans_kernel<<<dim3(32, 64), 256, 0, stream>>>(Vb, Vtb);
  attn_kernel<<<512, 512, 0, stream>>>(Qb, Kb, Vtb, ctxb);
  gemm_kernel<1><<<dim3(64, 8), 256, 0, stream>>>(ctxb, Wot, nullptr, out, bo, 8192, 1024, 1024);
}

// Round 4
// 319.368 us; speedup vs baseline: 1.5084x; 1.1187x over previous
//
#include <hip/hip_runtime.h>
#include <stdint.h>

#define B_   4
#define S_   2048
#define DI   1024
#define DOUT 1024
#define NHD  16
#define HD   64

typedef __attribute__((ext_vector_type(8))) short short8;
typedef __attribute__((ext_vector_type(4))) float f32x4;
typedef __attribute__((ext_vector_type(16))) float f32x16;

__device__ __forceinline__ unsigned short f32_bf16(float f) {
  union { float f; unsigned u; } v; v.f = f;
  unsigned r = v.u + 0x7FFFu + ((v.u >> 16) & 1u);   // RNE
  return (unsigned short)(r >> 16);
}

__device__ __forceinline__ unsigned pack_bf16x2(float a, float b) {
  union { float f; unsigned u; } x, y; x.f = a; y.f = b;
  return ((y.u + 0x8000u) & 0xFFFF0000u) | ((x.u + 0x8000u) >> 16);
}

// async 16B global->LDS (dst wave-uniform; HW adds lane*16)
__device__ __forceinline__ void gl_lds16(const void* g, void* s) {
  __builtin_amdgcn_global_load_lds(
      (const __attribute__((address_space(1))) unsigned int*)g,
      (__attribute__((address_space(3))) unsigned int*)s, 16, 0, 0);
}

// ---------- elementwise fp32 -> bf16 ----------
__global__ __launch_bounds__(256) void cvt_kernel(const float* __restrict__ src,
                                                  unsigned short* __restrict__ dst, int n4) {
  int i = blockIdx.x * blockDim.x + threadIdx.x;
  if (i < n4) {
    float4 v = ((const float4*)src)[i];
    ushort4 o;
    o.x = f32_bf16(v.x); o.y = f32_bf16(v.y); o.z = f32_bf16(v.z); o.w = f32_bf16(v.w);
    ((ushort4*)dst)[i] = o;
  }
}

// ---------- weight transpose+convert: W[k][n] f32 -> Wt[n][k] bf16 ----------
__global__ __launch_bounds__(256) void wtrans_kernel(const float* __restrict__ W,
                                                     unsigned short* __restrict__ Wt) {
  __shared__ __attribute__((aligned(16))) float tile[64][65];
  const int k0 = blockIdx.y * 64;
  const int n0 = blockIdx.x * 64;
  const int tid = threadIdx.x;
#pragma unroll
  for (int i = 0; i < 4; i++) {
    int c = tid + i * 256;
    int r = c >> 4;
    int cc = (c & 15) * 4;
    float4 v = *(const float4*)(W + (size_t)(k0 + r) * DOUT + n0 + cc);
    tile[r][cc] = v.x; tile[r][cc + 1] = v.y; tile[r][cc + 2] = v.z; tile[r][cc + 3] = v.w;
  }
  __syncthreads();
#pragma unroll
  for (int i = 0; i < 4; i++) {
    int c = tid + i * 256;
    int r = c >> 4;
    int cc = (c & 15) * 4;
    ushort4 o;
    o.x = f32_bf16(tile[cc + 0][r]);
    o.y = f32_bf16(tile[cc + 1][r]);
    o.z = f32_bf16(tile[cc + 2][r]);
    o.w = f32_bf16(tile[cc + 3][r]);
    *(ushort4*)(Wt + (size_t)(n0 + r) * DI + k0 + cc) = o;
  }
}

// ---------- V transpose: Vb[bh][s][hd] -> Vt[bh][hd][s] (bf16) ----------
__global__ __launch_bounds__(256) void vtrans_kernel(const unsigned short* __restrict__ Vb,
                                                     unsigned short* __restrict__ Vt) {
  __shared__ __attribute__((aligned(16))) unsigned short tile[64][72];
  const int bh = blockIdx.y;
  const int s0 = blockIdx.x * 64;
  const int tid = threadIdx.x;
  const unsigned short* src = Vb + (size_t)bh * S_ * HD + (size_t)s0 * HD;
#pragma unroll
  for (int i = 0; i < 2; i++) {
    int c = tid + i * 256;
    int r = c >> 3;
    int cc = (c & 7) * 8;
    *(uint4*)(&tile[r][cc]) = *(const uint4*)(src + r * HD + cc);
  }
  __syncthreads();
  unsigned short* dst = Vt + (size_t)bh * HD * S_ + s0;
#pragma unroll
  for (int i = 0; i < 2; i++) {
    int c = tid + i * 256;
    int r = c >> 3;
    int cc = (c & 7) * 8;
    union { unsigned short u[8]; uint4 v; } t;
#pragma unroll
    for (int j = 0; j < 8; j++) t.u[j] = tile[cc + j][r];
    *(uint4*)(dst + (size_t)r * S_ + cc) = t.v;
  }
}

// ---------- GEMM (m97 recipe). MODE 0: fused QKV (N=3072) scatter to head-major.
// MODE 1: fp32 row-major + bias. ----------
template <int MODE>
__global__ __launch_bounds__(256) void gemm_kernel(
    const unsigned short* __restrict__ A,
    const unsigned short* __restrict__ Bt,
    unsigned short* __restrict__ oQ,
    unsigned short* __restrict__ oK,
    unsigned short* __restrict__ oV,
    float* __restrict__ outF,
    const float* __restrict__ bias,
    int M, int N, int K) {
  __shared__ __attribute__((aligned(16))) unsigned short Asm_[128 * 32];
  __shared__ __attribute__((aligned(16))) unsigned short Bsm_[128 * 32];
  const int tid = threadIdx.x;
  const int lane = tid & 63;
  const int w = tid >> 6;
  const int wm = w >> 1, wn = w & 1;
  const int quad = lane >> 4, l16 = lane & 15;
  const int m0 = blockIdx.x * 128;
  const int n0 = blockIdx.y * 128;

  const int lr = lane >> 2;
  const int lc8 = (lane & 3) * 8;
  const unsigned short* gA0 = A + (size_t)(m0 + w * 32 + lr) * K + lc8;
  const unsigned short* gA1 = gA0 + (size_t)16 * K;
  const unsigned short* gB0 = Bt + (size_t)(n0 + w * 32 + lr) * K + lc8;
  const unsigned short* gB1 = gB0 + (size_t)16 * K;
  unsigned short* sA0 = Asm_ + (w * 2 + 0) * 512;
  unsigned short* sA1 = Asm_ + (w * 2 + 1) * 512;
  unsigned short* sB0 = Bsm_ + (w * 2 + 0) * 512;
  unsigned short* sB1 = Bsm_ + (w * 2 + 1) * 512;

  f32x4 acc[4][4] = {};

  for (int k0 = 0; k0 < K; k0 += 32) {
    __syncthreads();
    gl_lds16(gA0 + k0, sA0);
    gl_lds16(gA1 + k0, sA1);
    gl_lds16(gB0 + k0, sB0);
    gl_lds16(gB1 + k0, sB1);
    __syncthreads();
    short8 af[4], bfr[4];
#pragma unroll
    for (int mi = 0; mi < 4; mi++)
      af[mi] = *(const short8*)(Asm_ + (wm * 64 + mi * 16 + l16) * 32 + quad * 8);
#pragma unroll
    for (int ni = 0; ni < 4; ni++)
      bfr[ni] = *(const short8*)(Bsm_ + (wn * 64 + ni * 16 + l16) * 32 + quad * 8);
#pragma unroll
    for (int mi = 0; mi < 4; mi++)
#pragma unroll
      for (int ni = 0; ni < 4; ni++)
        acc[mi][ni] = __builtin_amdgcn_mfma_f32_16x16x32_bf16(af[mi], bfr[ni], acc[mi][ni], 0, 0, 0);
  }

  unsigned short* dst0 = nullptr;
  if (MODE == 0) {
    const int which = n0 >> 10;                 // block-uniform: 0=Q,1=K,2=V
    dst0 = which == 0 ? oQ : which == 1 ? oK : oV;
  }
#pragma unroll
  for (int mi = 0; mi < 4; mi++) {
#pragma unroll
    for (int ni = 0; ni < 4; ni++) {
      const int col = n0 + wn * 64 + ni * 16 + l16;
      float bv = (MODE == 1) ? bias[col] : 0.f;
#pragma unroll
      for (int r = 0; r < 4; r++) {
        const int row = m0 + wm * 64 + mi * 16 + quad * 4 + r;
        if (MODE == 0) {
          int b = row >> 11, s = row & 2047;
          int h = (col >> 6) & 15, hd = col & 63;
          dst0[(((size_t)(b * NHD + h)) * S_ + s) * HD + hd] = f32_bf16(acc[mi][ni][r]);
        } else {
          outF[(size_t)row * N + col] = acc[mi][ni][r] + bv;
        }
      }
    }
  }
}

// ================= flash attention helpers =================
__device__ __forceinline__ void softmax_tile(f32x16 (&s)[2], float& m_run, float& l_run,
                                             f32x16 (&oacc)[2], bool diag,
                                             int qrow, int k0, int h) {
  const float scl = 0.18033688f;   // (1/sqrt(64)) * log2(e)
  if (diag) {
#pragma unroll
    for (int mi = 0; mi < 2; mi++)
#pragma unroll
      for (int e = 0; e < 16; e++) {
        int key = k0 + mi * 32 + (e & 3) + 8 * (e >> 2) + 4 * h;
        if (key > qrow) s[mi][e] = -__builtin_inff();
      }
  }
  float vmax = -__builtin_inff();
#pragma unroll
  for (int mi = 0; mi < 2; mi++)
#pragma unroll
    for (int e = 0; e < 16; e++) vmax = fmaxf(vmax, s[mi][e]);
  vmax = fmaxf(vmax, __shfl_xor(vmax, 32));
  const float mnew = fmaxf(m_run, vmax * scl);
  const float alpha = exp2f(m_run - mnew);
  m_run = mnew;
  float rs = 0.f;
#pragma unroll
  for (int mi = 0; mi < 2; mi++)
#pragma unroll
    for (int e = 0; e < 16; e++) {
      float p = exp2f(fmaf(s[mi][e], scl, -mnew));
      s[mi][e] = p;
      rs += p;
    }
  rs += __shfl_xor(rs, 32);
  l_run = l_run * alpha + rs;
  oacc[0] *= alpha;
  oacc[1] *= alpha;
}

__device__ __forceinline__ void pv_tile(const f32x16 (&s)[2], f32x16 (&oacc)[2],
                                        const short8 (&vf)[4][2],
                                        unsigned short* myP, int l32, int h) {
#pragma unroll
  for (int mi = 0; mi < 2; mi++)
#pragma unroll
    for (int g2 = 0; g2 < 4; g2++) {
      uint2 pk;
      pk.x = pack_bf16x2(s[mi][4 * g2 + 0], s[mi][4 * g2 + 1]);
      pk.y = pack_bf16x2(s[mi][4 * g2 + 2], s[mi][4 * g2 + 3]);
      *(uint2*)(myP + l32 * 72 + mi * 32 + g2 * 8 + h * 4) = pk;
    }
#pragma unroll
  for (int ks2 = 0; ks2 < 4; ks2++) {
    short8 pf = *(const short8*)(myP + l32 * 72 + ks2 * 16 + h * 8);
#pragma unroll
    for (int mi2 = 0; mi2 < 2; mi2++)
      oacc[mi2] = __builtin_amdgcn_mfma_f32_32x32x16_bf16(vf[ks2][mi2], pf, oacc[mi2], 0, 0, 0);
  }
}

__device__ __forceinline__ void store_chunk(const f32x16 (&o)[2], float l_run, int qc,
                                            unsigned short* myP, unsigned short* ctx,
                                            int bh, int lane, int l32, int h) {
  const float inv = 1.f / l_run;
#pragma unroll
  for (int mi2 = 0; mi2 < 2; mi2++)
#pragma unroll
    for (int g2 = 0; g2 < 4; g2++) {
      uint2 pk;
      pk.x = pack_bf16x2(o[mi2][4 * g2 + 0] * inv, o[mi2][4 * g2 + 1] * inv);
      pk.y = pack_bf16x2(o[mi2][4 * g2 + 2] * inv, o[mi2][4 * g2 + 3] * inv);
      *(uint2*)(myP + l32 * 72 + mi2 * 32 + g2 * 8 + h * 4) = pk;
    }
  const int b = bh >> 4, head = bh & 15;
#pragma unroll
  for (int p = 0; p < 4; p++) {
    int r = p * 8 + (lane >> 3);
    int c = (lane & 7) * 8;
    uint4 vv = *(const uint4*)(myP + r * 72 + c);
    *(uint4*)(ctx + ((size_t)(b * S_ + qc * 32 + r)) * DOUT + head * 64 + c) = vv;
  }
}

// ---------- flash attention, causal — S^T form, complementary chunk pairing ----------
// Wave owns chunks qcA=63-g (heavy) and qcB=g (light): uniform total work (~33 tiles),
// shared kf/vf in the overlap phase (2x work/byte, 2x ILP). 256 blocks = 1/CU, no tail.
__global__ __launch_bounds__(512, 2) void attn_kernel(
    const unsigned short* __restrict__ Q,
    const unsigned short* __restrict__ Kmat,
    const unsigned short* __restrict__ Vt,
    unsigned short* __restrict__ ctx) {
  __shared__ __attribute__((aligned(16))) unsigned short PsT[256 * 72];

  const int tid = threadIdx.x;
  const int lane = tid & 63;
  const int w = tid >> 6;
  const int l32 = lane & 31;
  const int h = lane >> 5;

  const int bh = blockIdx.x & 63;          // 4 same-bh blocks land on same XCD (64%8==0)
  const int g = (blockIdx.x >> 6) * 8 + w; // 0..31
  const int qcA = 63 - g, qcB = g;
  const int ntA = (qcA >> 1) + 1;          // 17..32
  const int ntB = (qcB >> 1) + 1;          // 1..16  (always < ntA)

  const unsigned short* Qh = Q + (size_t)bh * S_ * HD;
  const unsigned short* Kh = Kmat + (size_t)bh * S_ * HD;
  const unsigned short* Vh = Vt + (size_t)bh * HD * S_;

  const int qrowA = qcA * 32 + l32;
  const int qrowB = qcB * 32 + l32;

  short8 qfA[4], qfB[4];
#pragma unroll
  for (int ks = 0; ks < 4; ks++) {
    qfA[ks] = *(const short8*)(Qh + (size_t)qrowA * HD + ks * 16 + h * 8);
    qfB[ks] = *(const short8*)(Qh + (size_t)qrowB * HD + ks * 16 + h * 8);
  }

  f32x16 oA[2] = {}, oB[2] = {};
  float mA = -__builtin_inff(), lA = 0.f;
  float mB = -__builtin_inff(), lB = 0.f;
  unsigned short* myP = PsT + (size_t)(w * 32) * 72;

  // ---- phase 1: both chunks, shared kf/vf ----
  for (int kt = 0; kt < ntB; kt++) {
    const int k0 = kt * 64;
    f32x16 sA[2] = {}, sB[2] = {};
#pragma unroll
    for (int ks = 0; ks < 4; ks++)
#pragma unroll
      for (int mi = 0; mi < 2; mi++) {
        short8 kf = *(const short8*)(Kh + (size_t)(k0 + mi * 32 + l32) * HD + ks * 16 + h * 8);
        sA[mi] = __builtin_amdgcn_mfma_f32_32x32x16_bf16(kf, qfA[ks], sA[mi], 0, 0, 0);
        sB[mi] = __builtin_amdgcn_mfma_f32_32x32x16_bf16(kf, qfB[ks], sB[mi], 0, 0, 0);
      }
    short8 vf[4][2];
#pragma unroll
    for (int ks2 = 0; ks2 < 4; ks2++)
#pragma unroll
      for (int mi2 = 0; mi2 < 2; mi2++)
        vf[ks2][mi2] = *(const short8*)(Vh + (size_t)(mi2 * 32 + l32) * S_ + k0 + ks2 * 16 + h * 8);
    softmax_tile(sA, mA, lA, oA, false, qrowA, k0, h);
    softmax_tile(sB, mB, lB, oB, kt == ntB - 1, qrowB, k0, h);
    pv_tile(sA, oA, vf, myP, l32, h);
    pv_tile(sB, oB, vf, myP, l32, h);
  }

  // ---- phase 2: chunk A only ----
  for (int kt = ntB; kt < ntA; kt++) {
    const int k0 = kt * 64;
    short8 vf[4][2];
#pragma unroll
    for (int ks2 = 0; ks2 < 4; ks2++)
#pragma unroll
      for (int mi2 = 0; mi2 < 2; mi2++)
        vf[ks2][mi2] = *(const short8*)(Vh + (size_t)(mi2 * 32 + l32) * S_ + k0 + ks2 * 16 + h * 8);
    f32x16 sA[2] = {};
#pragma unroll
    for (int ks = 0; ks < 4; ks++)
#pragma unroll
      for (int mi = 0; mi < 2; mi++) {
        short8 kf = *(const short8*)(Kh + (size_t)(k0 + mi * 32 + l32) * HD + ks * 16 + h * 8);
        sA[mi] = __builtin_amdgcn_mfma_f32_32x32x16_bf16(kf, qfA[ks], sA[mi], 0, 0, 0);
      }
    softmax_tile(sA, mA, lA, oA, kt == ntA - 1, qrowA, k0, h);
    pv_tile(sA, oA, vf, myP, l32, h);
  }

  store_chunk(oA, lA, qcA, myP, ctx, bh, lane, l32, h);
  store_chunk(oB, lB, qcB, myP, ctx, bh, lane, l32, h);
}

extern "C" void kernel_launch(void* const* d_in, const int* in_sizes, int n_in,
                              void* d_out, int out_size, void* d_ws, size_t ws_size,
                              hipStream_t stream) {
  const float* x  = (const float*)d_in[0];
  const float* Wq = (const float*)d_in[1];
  const float* Wk = (const float*)d_in[2];
  const float* Wv = (const float*)d_in[3];
  const float* Wo = (const float*)d_in[4];
  const float* bo = (const float*)d_in[5];
  float* out = (float*)d_out;
  char* ws = (char*)d_ws;

  const size_t MB = 1024 * 1024;
  unsigned short* Wqt = (unsigned short*)(ws + 0 * MB);   // contiguous 6 MB: QKV weights
  unsigned short* Wkt = (unsigned short*)(ws + 2 * MB);
  unsigned short* Wvt = (unsigned short*)(ws + 4 * MB);
  unsigned short* Wot = (unsigned short*)(ws + 6 * MB);
  unsigned short* xb  = (unsigned short*)(ws + 8 * MB);
  unsigned short* Qb  = (unsigned short*)(ws + 24 * MB);
  unsigned short* Kb  = (unsigned short*)(ws + 40 * MB);
  unsigned short* Vb  = (unsigned short*)(ws + 56 * MB);
  unsigned short* Vtb = (unsigned short*)(ws + 72 * MB);
  unsigned short* ctxb = xb;   // xb dead after QKV GEMM

  cvt_kernel<<<8192, 256, 0, stream>>>(x, xb, 2097152);
  wtrans_kernel<<<dim3(16, 16), 256, 0, stream>>>(Wq, Wqt);
  wtrans_kernel<<<dim3(16, 16), 256, 0, stream>>>(Wk, Wkt);
  wtrans_kernel<<<dim3(16, 16), 256, 0, stream>>>(Wv, Wvt);
  wtrans_kernel<<<dim3(16, 16), 256, 0, stream>>>(Wo, Wot);
  // fused QKV projection: N=3072 over contiguous [Wqt|Wkt|Wvt]
  gemm_kernel<0><<<dim3(64, 24), 256, 0, stream>>>(xb, Wqt, Qb, Kb, Vb, nullptr, nullptr,
                                                   8192, 3072, 1024);
  vtrans_kernel<<<dim3(32, 64), 256, 0, stream>>>(Vb, Vtb);
  attn_kernel<<<256, 512, 0, stream>>>(Qb, Kb, Vtb, ctxb);
  gemm_kernel<1><<<dim3(64, 8), 256, 0, stream>>>(ctxb, Wot, nullptr, nullptr, nullptr, out, bo,
                                                  8192, 1024, 1024);
}